// Round 3
// baseline (318.633 us; speedup 1.0000x reference)
//
#include <hip/hip_runtime.h>
#include <hip/hip_bf16.h>

// GARCH-LSTM fused cell, B=2097152 rows, H=16.
// Layout: 4 threads per row; each thread handles 4 hidden units via float4
// loads/stores of c_prev / c_t (perfectly coalesced, 16 B/lane).
// Memory-bound: 140 B/row ideal -> ~294 MB -> ~47 us floor at 6.3 TB/s.
// R3 change: drop LDS + __syncthreads entirely; weights read per-thread as
// float4 from global (L1/L2-resident after first touch). Removes the
// divergent staging prologue and per-block barrier serialization.

__device__ __forceinline__ float fsig(float x) {
    // sigmoid via fast exp2-based exp + raw v_rcp_f32 (abs threshold is 0.112)
    return __builtin_amdgcn_rcpf(1.0f + __expf(-x));
}

__device__ __forceinline__ float ftanh(float x) {
    // tanh(x) = 1 - 2/(exp(2x)+1); saturates correctly via exp overflow
    float t = __expf(2.0f * x);
    return 1.0f - 2.0f * __builtin_amdgcn_rcpf(t + 1.0f);
}

__global__ __launch_bounds__(256) void garch_lstm_kernel(
    const float* __restrict__ eps, const float* __restrict__ sigma2,
    const float* __restrict__ c_prev,
    const float* __restrict__ Wf_w, const float* __restrict__ Wf_b,
    const float* __restrict__ Uf_w, const float* __restrict__ Uf_b,
    const float* __restrict__ Wi_w, const float* __restrict__ Wi_b,
    const float* __restrict__ Ui_w, const float* __restrict__ Ui_b,
    const float* __restrict__ Wc_w, const float* __restrict__ Wc_b,
    const float* __restrict__ Uc_w, const float* __restrict__ Uc_b,
    const float* __restrict__ b_f, const float* __restrict__ b_i,
    const float* __restrict__ b_c, const float* __restrict__ w,
    const float* __restrict__ garch_w, const float* __restrict__ garch_b,
    float* __restrict__ out_s, float* __restrict__ out_c, int nrows)
{
    const unsigned tid = blockIdx.x * 256u + threadIdx.x;
    const unsigned row = tid >> 2;
    const unsigned sub = tid & 3u;
    if ((int)row >= nrows) return;

    // Issue the HBM-bound loads first so they're in flight during the
    // (cache-resident) weight loads below.
    const float e = eps[row];       // 4 lanes share one address -> 64B/wave
    const float s = sigma2[row];
    const float4 cp4 = *(reinterpret_cast<const float4*>(c_prev) + ((size_t)row * 4 + sub));
    const float cp[4] = {cp4.x, cp4.y, cp4.z, cp4.w};

    // Per-thread weight fragments: 4 contiguous, 16B-aligned floats each.
    // All 12 arrays total 768 B -> L1-resident after first touch per CU.
    const int h0 = (int)sub * 4;
    const float4 af = *reinterpret_cast<const float4*>(Wf_w + h0);
    const float4 bf = *reinterpret_cast<const float4*>(Uf_w + h0);
    const float4 ai = *reinterpret_cast<const float4*>(Wi_w + h0);
    const float4 bi = *reinterpret_cast<const float4*>(Ui_w + h0);
    const float4 ac = *reinterpret_cast<const float4*>(Wc_w + h0);
    const float4 bc = *reinterpret_cast<const float4*>(Uc_w + h0);
    const float4 wfb = *reinterpret_cast<const float4*>(Wf_b + h0);
    const float4 ufb = *reinterpret_cast<const float4*>(Uf_b + h0);
    const float4 wib = *reinterpret_cast<const float4*>(Wi_b + h0);
    const float4 uib = *reinterpret_cast<const float4*>(Ui_b + h0);
    const float4 wcb = *reinterpret_cast<const float4*>(Wc_b + h0);
    const float4 ucb = *reinterpret_cast<const float4*>(Uc_b + h0);
    // Wave-uniform scalars -> s_load.
    const float bf0 = b_f[0], bi0 = b_i[0], bc0 = b_c[0];
    const float g1 = garch_w[1], g2 = garch_w[2], g3 = garch_w[3];
    const float g0 = garch_w[0] /*×SCALE=1*/ + garch_b[0];
    const float wv = w[0];

    const float Af[4] = {af.x, af.y, af.z, af.w};
    const float Bf[4] = {bf.x, bf.y, bf.z, bf.w};
    const float Cf[4] = {wfb.x + ufb.x + bf0, wfb.y + ufb.y + bf0,
                         wfb.z + ufb.z + bf0, wfb.w + ufb.w + bf0};
    const float Ai[4] = {ai.x, ai.y, ai.z, ai.w};
    const float Bi[4] = {bi.x, bi.y, bi.z, bi.w};
    const float Ci[4] = {wib.x + uib.x + bi0, wib.y + uib.y + bi0,
                         wib.z + uib.z + bi0, wib.w + uib.w + bi0};
    const float Ac[4] = {ac.x, ac.y, ac.z, ac.w};
    const float Bc[4] = {bc.x, bc.y, bc.z, bc.w};
    const float Cc[4] = {wcb.x + ucb.x + bc0, wcb.y + ucb.y + bc0,
                         wcb.z + ucb.z + bc0, wcb.w + ucb.w + bc0};

    float cv[4];
    float sum_t = 0.0f;
#pragma unroll
    for (int j = 0; j < 4; ++j) {
        const float pf = fmaf(e, Af[j], fmaf(s, Bf[j], Cf[j]));
        const float pi = fmaf(e, Ai[j], fmaf(s, Bi[j], Ci[j]));
        const float pc = fmaf(e, Ac[j], fmaf(s, Bc[j], Cc[j]));
        const float f_t   = fsig(pf);
        const float i_t   = fsig(pi);
        const float c_hat = fsig(pc);   // reference uses sigmoid for c_hat
        const float c = fmaf(i_t, c_hat, f_t * cp[j]);
        cv[j] = c;
        sum_t += ftanh(c);
    }

    // Coalesced float4 store of c_t
    float4 ct4 = make_float4(cv[0], cv[1], cv[2], cv[3]);
    *(reinterpret_cast<float4*>(out_c) + ((size_t)row * 4 + sub)) = ct4;

    // Reduce tanh-sum across the 4 lanes of this row
    sum_t += __shfl_xor(sum_t, 1, 64);
    sum_t += __shfl_xor(sum_t, 2, 64);

    if (sub == 0) {
        const float e2 = e * e;
        const float asym = (e < 0.0f) ? e2 : 0.0f;
        const float o = fmaf(g1, e2, fmaf(g2, asym, fmaf(g3, s, g0)));
        // 16 active lanes/wave write 16 consecutive floats -> one 64B line.
        out_s[row] = o * fmaf(wv, sum_t * 0.0625f, 1.0f);
    }
}

extern "C" void kernel_launch(void* const* d_in, const int* in_sizes, int n_in,
                              void* d_out, int out_size, void* d_ws, size_t ws_size,
                              hipStream_t stream) {
    // setup_inputs() dict order:
    // 0 eps, 1 sigma2, 2 c_prev, 3..14 {Wf_w,Wf_b,Uf_w,Uf_b,Wi_w,Wi_b,Ui_w,Ui_b,
    // Wc_w,Wc_b,Uc_w,Uc_b}, 15 b_f, 16 b_i, 17 b_c, 18 w, 19 garch_w, 20 garch_b
    const float* eps     = (const float*)d_in[0];
    const float* sigma2  = (const float*)d_in[1];
    const float* c_prev  = (const float*)d_in[2];
    const float* Wf_w    = (const float*)d_in[3];
    const float* Wf_b    = (const float*)d_in[4];
    const float* Uf_w    = (const float*)d_in[5];
    const float* Uf_b    = (const float*)d_in[6];
    const float* Wi_w    = (const float*)d_in[7];
    const float* Wi_b    = (const float*)d_in[8];
    const float* Ui_w    = (const float*)d_in[9];
    const float* Ui_b    = (const float*)d_in[10];
    const float* Wc_w    = (const float*)d_in[11];
    const float* Wc_b    = (const float*)d_in[12];
    const float* Uc_w    = (const float*)d_in[13];
    const float* Uc_b    = (const float*)d_in[14];
    const float* b_f     = (const float*)d_in[15];
    const float* b_i     = (const float*)d_in[16];
    const float* b_c     = (const float*)d_in[17];
    const float* wp      = (const float*)d_in[18];
    const float* garch_w = (const float*)d_in[19];
    const float* garch_b = (const float*)d_in[20];

    const int n = in_sizes[0];          // B = 2097152
    float* out_s = (float*)d_out;       // (B,1) first in return order
    float* out_c = out_s + n;           // (B,16) second

    const int threads = 256;
    const long long total = (long long)n * 4;   // 4 threads per row
    const int blocks = (int)((total + threads - 1) / threads);

    garch_lstm_kernel<<<blocks, threads, 0, stream>>>(
        eps, sigma2, c_prev,
        Wf_w, Wf_b, Uf_w, Uf_b, Wi_w, Wi_b, Ui_w, Ui_b,
        Wc_w, Wc_b, Uc_w, Uc_b, b_f, b_i, b_c, wp, garch_w, garch_b,
        out_s, out_c, n);
}